// Round 1
// baseline (346.919 us; speedup 1.0000x reference)
//
#include <hip/hip_runtime.h>

#define DIMC 512
#define NTOK 4097
#define GH 64
#define GW 64
#define TH 16

// Fold w7 + padded(w5) + padded(w3) + identity into one 7x7 depthwise kernel,
// stored tap-major [t][c] so lanes (channels) read coalesced. Bias = b7+b5+b3.
__global__ __launch_bounds__(256) void prep_kernel(
    const float* __restrict__ w7, const float* __restrict__ b7,
    const float* __restrict__ w5, const float* __restrict__ b5,
    const float* __restrict__ w3, const float* __restrict__ b3,
    float* __restrict__ wc, float* __restrict__ bc)
{
    int idx = blockIdx.x * 256 + threadIdx.x;   // 0 .. 512*49-1
    if (idx < DIMC * 49) {
        int c = idx & (DIMC - 1);
        int t = idx >> 9;
        int dy = t / 7, dx = t - dy * 7;
        float v = w7[c * 49 + t];
        if (dy >= 1 && dy <= 5 && dx >= 1 && dx <= 5)
            v += w5[c * 25 + (dy - 1) * 5 + (dx - 1)];
        if (dy >= 2 && dy <= 4 && dx >= 2 && dx <= 4)
            v += w3[c * 9 + (dy - 2) * 3 + (dx - 2)];
        if (dy == 3 && dx == 3) v += 1.0f;      // identity (residual) term
        wc[t * DIMC + c] = v;
    }
    if (idx < DIMC) bc[idx] = b7[idx] + b5[idx] + b3[idx];
}

// cls token pass-through: out[b,0,:] = x[b,0,:]
__global__ __launch_bounds__(256) void cls_kernel(
    const float* __restrict__ x, float* __restrict__ out)
{
    int i = blockIdx.x * 256 + threadIdx.x;     // 0 .. 16*512-1
    int b = i >> 9, c = i & 511;
    size_t off = (size_t)b * NTOK * DIMC + c;
    out[off] = x[off];
}

// Depthwise combined 7x7 conv over the (64,64) grid, channels on lanes.
// Thread = (channel, w-column); computes TH consecutive output rows using a
// rolling 7x7 register window (7 global loads per input row, each coalesced
// 256B across the 64 channel-lanes of the wave).
__global__ __launch_bounds__(256) void dwconv_kernel(
    const float* __restrict__ x, const float* __restrict__ wc,
    const float* __restrict__ bc, float* __restrict__ out)
{
    const int c_in_chunk = threadIdx.x;            // 0..63 (lane = channel)
    const int wlane = threadIdx.y;                 // 0..3
    const int wseg = blockIdx.x;                   // 0..15
    const int yid  = blockIdx.y;                   // 0..31 = cseg(8) x hseg(4)
    const int b    = blockIdx.z;                   // 0..15
    const int cc = (yid >> 2) * 64 + c_in_chunk;   // channel 0..511
    const int h0 = (yid & 3) * TH;                 // output row base
    const int w  = wseg * 4 + wlane;               // output column (wave-uniform)

    float wgt[49];
#pragma unroll
    for (int t = 0; t < 49; ++t) wgt[t] = wc[t * DIMC + cc];
    const float bias = bc[cc];

    const float* __restrict__ xin = x   + ((size_t)b * NTOK + 1) * DIMC + cc;
    float* __restrict__ op        = out + ((size_t)b * NTOK + 1) * DIMC + cc;

    float win[7][7];   // [slot][dx] rolling row window, fully register-promoted

    auto load_row = [&](int r, float* row) {
        if (r < 0 || r >= GH) {
#pragma unroll
            for (int dx = 0; dx < 7; ++dx) row[dx] = 0.0f;
        } else {
            const float* rp = xin + (size_t)r * GW * DIMC;
#pragma unroll
            for (int dx = 0; dx < 7; ++dx) {
                int col = w - 3 + dx;              // wave-uniform guard
                row[dx] = (col >= 0 && col < GW) ? rp[(size_t)col * DIMC] : 0.0f;
            }
        }
    };

    // Preload rows h0-3 .. h0+2 into slots 0..5
#pragma unroll
    for (int p = 0; p < 6; ++p) load_row(h0 - 3 + p, win[p]);

#pragma unroll
    for (int o = 0; o < TH; ++o) {
        load_row(h0 + o + 3, win[(o + 6) % 7]);    // newest row -> slot (o+6)%7
        float acc = bias;
#pragma unroll
        for (int dy = 0; dy < 7; ++dy) {
            const float* row = win[(o + dy) % 7];  // row h0+o+dy-3
#pragma unroll
            for (int dx = 0; dx < 7; ++dx)
                acc += wgt[dy * 7 + dx] * row[dx];
        }
        op[((size_t)(h0 + o) * GW + w) * DIMC] = acc;
    }
}

extern "C" void kernel_launch(void* const* d_in, const int* in_sizes, int n_in,
                              void* d_out, int out_size, void* d_ws, size_t ws_size,
                              hipStream_t stream)
{
    const float* x  = (const float*)d_in[0];
    const float* w7 = (const float*)d_in[1];
    const float* b7 = (const float*)d_in[2];
    const float* w5 = (const float*)d_in[3];
    const float* b5 = (const float*)d_in[4];
    const float* w3 = (const float*)d_in[5];
    const float* b3 = (const float*)d_in[6];
    float* out = (float*)d_out;
    float* wcomb = (float*)d_ws;            // 49*512 floats
    float* bcomb = wcomb + 49 * DIMC;       // 512 floats

    prep_kernel<<<98, 256, 0, stream>>>(w7, b7, w5, b5, w3, b3, wcomb, bcomb);
    cls_kernel<<<32, 256, 0, stream>>>(x, out);

    dim3 grid(16, 32, 16);                  // wseg x (cseg*4+hseg) x batch
    dim3 block(64, 4, 1);                   // 64 channel-lanes x 4 w-columns
    dwconv_kernel<<<grid, block, 0, stream>>>(x, wcomb, bcomb, out);
}